// Round 1
// baseline (388.244 us; speedup 1.0000x reference)
//
#include <hip/hip_runtime.h>

#define N_EMB   8192
#define D_EMB   128
#define NSTEPS  201
#define STEPF   0.01f
#define NB      128                  // 8192 / 64 tiles per dim
#define TBLOCKS (NB*(NB+1)/2)        // 8256 upper-tri tiles incl. diagonal
#define NCOPY   16                   // replicated global histograms

typedef __attribute__((ext_vector_type(8))) short bf16x8;
typedef __attribute__((ext_vector_type(4))) float f32x4;

__device__ __forceinline__ unsigned short f2bf(float f) {
  unsigned int u = __builtin_bit_cast(unsigned int, f);
  u = (u + 0x7fffu + ((u >> 16) & 1u)) >> 16;   // RNE fp32 -> bf16
  return (unsigned short)u;
}

__global__ __launch_bounds__(256, 4) void hist_kernel(
    const float* __restrict__ x1, const float* __restrict__ x2,
    const float* __restrict__ t1, const float* __restrict__ t2,
    float* __restrict__ ghist, unsigned int* __restrict__ gcnt)
{
  __shared__ __align__(16) unsigned short As[64*128];   // bf16 bits, swizzled 16B chunks
  __shared__ __align__(16) unsigned short Bs[64*128];
  __shared__ float sT1[64], sT2[64];
  __shared__ float whist[4][2][NSTEPS];                 // per-wave {pos,neg}
  __shared__ unsigned int blk_pos;

  const int tid = threadIdx.x;

  // ---- linear block id -> (bi, bj) with bi <= bj (upper triangle) ----
  int t   = (int)blockIdx.x;
  int rem = TBLOCKS - 1 - t;
  int r   = (int)((sqrtf(8.0f*(float)rem + 1.0f) - 1.0f) * 0.5f);
  while ((r+1)*(r+2)/2 <= rem) ++r;
  while (r*(r+1)/2 > rem) --r;
  const int bi  = NB - 1 - r;
  const int bj  = NB - 1 - (rem - r*(r+1)/2);
  const int gi0 = bi*64, gj0 = bj*64;

  // ---- zero per-wave histograms / counter ----
  for (int b = tid; b < 4*2*NSTEPS; b += 256) ((float*)whist)[b] = 0.0f;
  if (tid == 0) blk_pos = 0u;

  // ---- stage target vectors ----
  if (tid < 64)        sT2[tid]      = t2[gi0 + tid];
  else if (tid < 128)  sT1[tid - 64] = t1[gj0 + (tid - 64)];

  // ---- stage A (x1 rows) and B (x2 rows) tiles as bf16, swizzled chunks ----
  // chunk = 8 bf16 = 16B; tile = 64 rows x 16 chunks; swizzle chunk idx ^= (row&7)
  for (int it = 0; it < 4; ++it) {
    int f   = tid + it*256;          // 0..1023
    int row = f >> 4;
    int c   = f & 15;
    int dst = (row*16 + (c ^ (row & 7))) * 8;

    const float4* ga = reinterpret_cast<const float4*>(x1 + (size_t)(gi0+row)*D_EMB + c*8);
    float4 v0 = ga[0], v1 = ga[1];
    uint4 pa;
    pa.x = f2bf(v0.x) | ((unsigned int)f2bf(v0.y) << 16);
    pa.y = f2bf(v0.z) | ((unsigned int)f2bf(v0.w) << 16);
    pa.z = f2bf(v1.x) | ((unsigned int)f2bf(v1.y) << 16);
    pa.w = f2bf(v1.z) | ((unsigned int)f2bf(v1.w) << 16);
    *reinterpret_cast<uint4*>(&As[dst]) = pa;

    const float4* gb = reinterpret_cast<const float4*>(x2 + (size_t)(gj0+row)*D_EMB + c*8);
    float4 w0 = gb[0], w1 = gb[1];
    uint4 pb;
    pb.x = f2bf(w0.x) | ((unsigned int)f2bf(w0.y) << 16);
    pb.y = f2bf(w0.z) | ((unsigned int)f2bf(w0.w) << 16);
    pb.z = f2bf(w1.x) | ((unsigned int)f2bf(w1.y) << 16);
    pb.w = f2bf(w1.z) | ((unsigned int)f2bf(w1.w) << 16);
    *reinterpret_cast<uint4*>(&Bs[dst]) = pb;
  }
  __syncthreads();

  // ---- MFMA: 4 waves, each computes a 32x32 quadrant as 2x2 of 16x16 tiles ----
  const int lane = tid & 63;
  const int w    = tid >> 6;
  const int wr   = w >> 1, wc = w & 1;
  const int fr   = lane & 15;
  const int kg   = lane >> 4;

  const int rA0 = wr*32 + fr, rA1 = rA0 + 16;
  const int rB0 = wc*32 + fr, rB1 = rB0 + 16;

  f32x4 acc00 = {0.f,0.f,0.f,0.f}, acc01 = {0.f,0.f,0.f,0.f};
  f32x4 acc10 = {0.f,0.f,0.f,0.f}, acc11 = {0.f,0.f,0.f,0.f};

#pragma unroll
  for (int ks = 0; ks < 4; ++ks) {
    int cc = ks*4 + kg;
    bf16x8 a0 = *reinterpret_cast<const bf16x8*>(&As[(rA0*16 + (cc ^ (rA0 & 7))) * 8]);
    bf16x8 a1 = *reinterpret_cast<const bf16x8*>(&As[(rA1*16 + (cc ^ (rA1 & 7))) * 8]);
    bf16x8 b0 = *reinterpret_cast<const bf16x8*>(&Bs[(rB0*16 + (cc ^ (rB0 & 7))) * 8]);
    bf16x8 b1 = *reinterpret_cast<const bf16x8*>(&Bs[(rB1*16 + (cc ^ (rB1 & 7))) * 8]);
    acc00 = __builtin_amdgcn_mfma_f32_16x16x32_bf16(a0, b0, acc00, 0, 0, 0);
    acc01 = __builtin_amdgcn_mfma_f32_16x16x32_bf16(a0, b1, acc01, 0, 0, 0);
    acc10 = __builtin_amdgcn_mfma_f32_16x16x32_bf16(a1, b0, acc10, 0, 0, 0);
    acc11 = __builtin_amdgcn_mfma_f32_16x16x32_bf16(a1, b1, acc11, 0, 0, 0);
  }

  // ---- soft binning into per-wave LDS histograms ----
  // C/D layout (verified m89/m91): col = lane&15, row = (lane>>4)*4 + reg
  unsigned int cnt_pos = 0;
  float* hp = whist[w][0];
  float* hn = whist[w][1];
  const int rbase = kg * 4;

  auto binTile = [&](const f32x4& acc, int tm, int tn) {
    int lj = wc*32 + tn*16 + fr;
    int gj = gj0 + lj;
    float t1v = sT1[lj];
#pragma unroll
    for (int rr = 0; rr < 4; ++rr) {
      int li = wr*32 + tm*16 + rbase + rr;
      int gi = gi0 + li;
      if (gj > gi) {                       // strictly-upper pairs only
        float s   = acc[rr];
        float t2v = sT2[li];
        bool  pos = (t2v * t1v) > 0.0f;
        float u   = (s + 1.0f) / STEPF;
        int   idx = (int)floorf(u);
        idx = idx < 0 ? 0 : (idx > NSTEPS-1 ? NSTEPS-1 : idx);
        float delta = (float)idx * STEPF - 1.0f;
        float frac  = (s - delta) / STEPF;
        int   ih    = idx + 1; if (ih > NSTEPS-1) ih = NSTEPS-1;
        float* h = pos ? hp : hn;
        atomicAdd(&h[idx], 1.0f - frac);
        atomicAdd(&h[ih],  frac);
        cnt_pos += pos ? 1u : 0u;
      }
    }
  };
  binTile(acc00, 0, 0); binTile(acc01, 0, 1);
  binTile(acc10, 1, 0); binTile(acc11, 1, 1);

  atomicAdd(&blk_pos, cnt_pos);
  __syncthreads();

  // ---- flush block histogram into one of NCOPY global copies ----
  float* gh = ghist + (size_t)(blockIdx.x & (NCOPY-1)) * (2*NSTEPS);
  for (int b = tid; b < NSTEPS; b += 256) {
    float sp = whist[0][0][b] + whist[1][0][b] + whist[2][0][b] + whist[3][0][b];
    float sn = whist[0][1][b] + whist[1][1][b] + whist[2][1][b] + whist[3][1][b];
    atomicAdd(&gh[b],          sp);
    atomicAdd(&gh[NSTEPS + b], sn);
  }
  if (tid == 0) atomicAdd(gcnt, blk_pos);
}

__global__ void finalize_kernel(const float* __restrict__ ghist,
                                const unsigned int* __restrict__ gcnt,
                                float* __restrict__ out)
{
  __shared__ float hp[NSTEPS], hn[NSTEPS];
  const int tid = threadIdx.x;
  for (int b = tid; b < NSTEPS; b += 256) {
    float sp = 0.f, sn = 0.f;
    for (int c = 0; c < NCOPY; ++c) {
      sp += ghist[(size_t)c*(2*NSTEPS) + b];
      sn += ghist[(size_t)c*(2*NSTEPS) + NSTEPS + b];
    }
    hp[b] = sp; hn[b] = sn;
  }
  __syncthreads();
  if (tid == 0) {
    const unsigned long long TOT = (unsigned long long)N_EMB * (N_EMB-1) / 2;  // 33550336
    float pc = (float)gcnt[0];
    float nc = (float)(TOT - (unsigned long long)gcnt[0]);
    float pcd = fmaxf(pc, 1.0f), ncd = fmaxf(nc, 1.0f);
    float cdf = 0.f, loss = 0.f;
    for (int b = 0; b < NSTEPS; ++b) {
      cdf  += hp[b] / pcd;
      loss += (hn[b] / ncd) * cdf;
    }
    out[0] = loss;
  }
}

extern "C" void kernel_launch(void* const* d_in, const int* in_sizes, int n_in,
                              void* d_out, int out_size, void* d_ws, size_t ws_size,
                              hipStream_t stream) {
  const float* x1 = (const float*)d_in[0];
  const float* x2 = (const float*)d_in[1];
  const float* t1 = (const float*)d_in[2];
  const float* t2 = (const float*)d_in[3];
  float* out = (float*)d_out;

  float* ghist = (float*)d_ws;
  unsigned int* gcnt = (unsigned int*)((char*)d_ws + (size_t)NCOPY*2*NSTEPS*sizeof(float));

  hipMemsetAsync(d_ws, 0, (size_t)NCOPY*2*NSTEPS*sizeof(float) + sizeof(unsigned int), stream);
  hist_kernel<<<TBLOCKS, 256, 0, stream>>>(x1, x2, t1, t2, ghist, gcnt);
  finalize_kernel<<<1, 256, 0, stream>>>(ghist, gcnt, out);
}

// Round 2
// 143.169 us; speedup vs baseline: 2.7118x; 2.7118x over previous
//
#include <hip/hip_runtime.h>

#define N_EMB   8192
#define D_EMB   128
#define NSTEPS  201
#define STEPF   0.01f
#define NB      128                  // 8192 / 64 tiles per dim
#define TBLOCKS (NB*(NB+1)/2)        // 8256 upper-tri tiles incl. diagonal
#define NCOPY   64                   // replicated global histograms

typedef __attribute__((ext_vector_type(8))) short bf16x8;
typedef __attribute__((ext_vector_type(4))) float f32x4;

// packed per-bin accumulator: (count << 21) | round(frac * 1024)
#define FRAC_SCALE 1024.0f
#define CNT_SHIFT  21
#define FRAC_MASK  ((1u << CNT_SHIFT) - 1u)

__device__ __forceinline__ unsigned short f2bf(float f) {
  unsigned int u = __builtin_bit_cast(unsigned int, f);
  u = (u + 0x7fffu + ((u >> 16) & 1u)) >> 16;   // RNE fp32 -> bf16
  return (unsigned short)u;
}

__global__ __launch_bounds__(256, 4) void hist_kernel(
    const float* __restrict__ x1, const float* __restrict__ x2,
    const float* __restrict__ t1, const float* __restrict__ t2,
    float* __restrict__ ghist, unsigned int* __restrict__ gcnt)
{
  __shared__ __align__(16) unsigned short As[64*128];   // bf16 bits, swizzled 16B chunks
  __shared__ __align__(16) unsigned short Bs[64*128];
  __shared__ float sT1[64], sT2[64];
  __shared__ unsigned int whist[4][2][NSTEPS];          // per-wave {pos,neg} packed u32
  __shared__ unsigned int blk_pos;

  const int tid = threadIdx.x;

  // ---- linear block id -> (bi, bj) with bi <= bj (upper triangle) ----
  int t   = (int)blockIdx.x;
  int rem = TBLOCKS - 1 - t;
  int r   = (int)((sqrtf(8.0f*(float)rem + 1.0f) - 1.0f) * 0.5f);
  while ((r+1)*(r+2)/2 <= rem) ++r;
  while (r*(r+1)/2 > rem) --r;
  const int bi  = NB - 1 - r;
  const int bj  = NB - 1 - (rem - r*(r+1)/2);
  const int gi0 = bi*64, gj0 = bj*64;

  // ---- zero per-wave histograms / counter ----
  for (int b = tid; b < 4*2*NSTEPS; b += 256) ((unsigned int*)whist)[b] = 0u;
  if (tid == 0) blk_pos = 0u;

  // ---- stage target vectors ----
  if (tid < 64)        sT2[tid]      = t2[gi0 + tid];
  else if (tid < 128)  sT1[tid - 64] = t1[gj0 + (tid - 64)];

  // ---- stage A (x1 rows) and B (x2 rows) tiles as bf16, swizzled chunks ----
  for (int it = 0; it < 4; ++it) {
    int f   = tid + it*256;          // 0..1023
    int row = f >> 4;
    int c   = f & 15;
    int dst = (row*16 + (c ^ (row & 7))) * 8;

    const float4* ga = reinterpret_cast<const float4*>(x1 + (size_t)(gi0+row)*D_EMB + c*8);
    float4 v0 = ga[0], v1 = ga[1];
    uint4 pa;
    pa.x = f2bf(v0.x) | ((unsigned int)f2bf(v0.y) << 16);
    pa.y = f2bf(v0.z) | ((unsigned int)f2bf(v0.w) << 16);
    pa.z = f2bf(v1.x) | ((unsigned int)f2bf(v1.y) << 16);
    pa.w = f2bf(v1.z) | ((unsigned int)f2bf(v1.w) << 16);
    *reinterpret_cast<uint4*>(&As[dst]) = pa;

    const float4* gb = reinterpret_cast<const float4*>(x2 + (size_t)(gj0+row)*D_EMB + c*8);
    float4 w0 = gb[0], w1 = gb[1];
    uint4 pb;
    pb.x = f2bf(w0.x) | ((unsigned int)f2bf(w0.y) << 16);
    pb.y = f2bf(w0.z) | ((unsigned int)f2bf(w0.w) << 16);
    pb.z = f2bf(w1.x) | ((unsigned int)f2bf(w1.y) << 16);
    pb.w = f2bf(w1.z) | ((unsigned int)f2bf(w1.w) << 16);
    *reinterpret_cast<uint4*>(&Bs[dst]) = pb;
  }
  __syncthreads();

  // ---- MFMA: 4 waves, each computes a 32x32 quadrant as 2x2 of 16x16 tiles ----
  const int lane = tid & 63;
  const int w    = tid >> 6;
  const int wr   = w >> 1, wc = w & 1;
  const int fr   = lane & 15;
  const int kg   = lane >> 4;

  const int rA0 = wr*32 + fr, rA1 = rA0 + 16;
  const int rB0 = wc*32 + fr, rB1 = rB0 + 16;

  f32x4 acc00 = {0.f,0.f,0.f,0.f}, acc01 = {0.f,0.f,0.f,0.f};
  f32x4 acc10 = {0.f,0.f,0.f,0.f}, acc11 = {0.f,0.f,0.f,0.f};

#pragma unroll
  for (int ks = 0; ks < 4; ++ks) {
    int cc = ks*4 + kg;
    bf16x8 a0 = *reinterpret_cast<const bf16x8*>(&As[(rA0*16 + (cc ^ (rA0 & 7))) * 8]);
    bf16x8 a1 = *reinterpret_cast<const bf16x8*>(&As[(rA1*16 + (cc ^ (rA1 & 7))) * 8]);
    bf16x8 b0 = *reinterpret_cast<const bf16x8*>(&Bs[(rB0*16 + (cc ^ (rB0 & 7))) * 8]);
    bf16x8 b1 = *reinterpret_cast<const bf16x8*>(&Bs[(rB1*16 + (cc ^ (rB1 & 7))) * 8]);
    acc00 = __builtin_amdgcn_mfma_f32_16x16x32_bf16(a0, b0, acc00, 0, 0, 0);
    acc01 = __builtin_amdgcn_mfma_f32_16x16x32_bf16(a0, b1, acc01, 0, 0, 0);
    acc10 = __builtin_amdgcn_mfma_f32_16x16x32_bf16(a1, b0, acc10, 0, 0, 0);
    acc11 = __builtin_amdgcn_mfma_f32_16x16x32_bf16(a1, b1, acc11, 0, 0, 0);
  }

  // ---- soft binning: ONE packed u32 LDS atomic per pair ----
  // C/D layout (verified m89/m91): col = lane&15, row = (lane>>4)*4 + reg
  unsigned int* hp = whist[w][0];
  unsigned int* hn = whist[w][1];
  const int rbase = kg * 4;

  auto binTile = [&](const f32x4& acc, int tm, int tn) {
    int lj = wc*32 + tn*16 + fr;
    int gj = gj0 + lj;
    float t1v = sT1[lj];
#pragma unroll
    for (int rr = 0; rr < 4; ++rr) {
      int li = wr*32 + tm*16 + rbase + rr;
      int gi = gi0 + li;
      if (gj > gi) {                       // strictly-upper pairs only
        float s   = acc[rr];
        float t2v = sT2[li];
        bool  pos = (t2v * t1v) > 0.0f;
        float u   = (s + 1.0f) * 100.0f;   // (s+1)/step
        int   idx = (int)floorf(u);
        idx = idx < 0 ? 0 : (idx > NSTEPS-1 ? NSTEPS-1 : idx);
        float delta = (float)idx * STEPF - 1.0f;
        float frac  = (s - delta) * 100.0f;
        frac = fminf(fmaxf(frac, 0.0f), 1.0f);
        unsigned int pk = (1u << CNT_SHIFT) | (unsigned int)(frac * FRAC_SCALE + 0.5f);
        atomicAdd(pos ? &hp[idx] : &hn[idx], pk);
      }
    }
  };
  binTile(acc00, 0, 0); binTile(acc01, 0, 1);
  binTile(acc10, 1, 0); binTile(acc11, 1, 1);

  __syncthreads();

  // ---- unpack + flush block histogram into one of NCOPY global copies ----
  // h[b] = cnt[b] - fr[b] + fr[b-1]  (b<200);  h[200] = cnt[200] + fr[199]
  float* gh = ghist + (size_t)(blockIdx.x & (NCOPY-1)) * (2*NSTEPS);
  if (tid < NSTEPS) {
    const int b = tid;
    unsigned int cp = 0, cn = 0;
    float fp = 0.f, fn = 0.f, fpm1 = 0.f, fnm1 = 0.f;
#pragma unroll
    for (int ww = 0; ww < 4; ++ww) {
      unsigned int vp = whist[ww][0][b], vn = whist[ww][1][b];
      cp += vp >> CNT_SHIFT;  fp += (float)(vp & FRAC_MASK);
      cn += vn >> CNT_SHIFT;  fn += (float)(vn & FRAC_MASK);
      if (b > 0) {
        unsigned int vpm = whist[ww][0][b-1], vnm = whist[ww][1][b-1];
        fpm1 += (float)(vpm & FRAC_MASK);
        fnm1 += (float)(vnm & FRAC_MASK);
      }
    }
    const float inv = 1.0f / FRAC_SCALE;
    float hpv, hnv;
    if (b == NSTEPS-1) {                   // idx_hi clamp: frac stays in bin 200
      hpv = (float)cp + fpm1 * inv;
      hnv = (float)cn + fnm1 * inv;
    } else {
      hpv = (float)cp - fp * inv + fpm1 * inv;
      hnv = (float)cn - fn * inv + fnm1 * inv;
    }
    if (hpv != 0.0f) atomicAdd(&gh[b],          hpv);
    if (hnv != 0.0f) atomicAdd(&gh[NSTEPS + b], hnv);
    if (cp) atomicAdd(&blk_pos, cp);
  }
  __syncthreads();
  if (tid == 0 && blk_pos) atomicAdd(gcnt, blk_pos);
}

__global__ void finalize_kernel(const float* __restrict__ ghist,
                                const unsigned int* __restrict__ gcnt,
                                float* __restrict__ out)
{
  __shared__ float hp[NSTEPS], hn[NSTEPS];
  const int tid = threadIdx.x;
  for (int b = tid; b < NSTEPS; b += 256) {
    float sp = 0.f, sn = 0.f;
    for (int c = 0; c < NCOPY; ++c) {
      sp += ghist[(size_t)c*(2*NSTEPS) + b];
      sn += ghist[(size_t)c*(2*NSTEPS) + NSTEPS + b];
    }
    hp[b] = sp; hn[b] = sn;
  }
  __syncthreads();
  if (tid == 0) {
    const unsigned long long TOT = (unsigned long long)N_EMB * (N_EMB-1) / 2;  // 33550336
    float pc = (float)gcnt[0];
    float nc = (float)(TOT - (unsigned long long)gcnt[0]);
    float pcd = fmaxf(pc, 1.0f), ncd = fmaxf(nc, 1.0f);
    float cdf = 0.f, loss = 0.f;
    for (int b = 0; b < NSTEPS; ++b) {
      cdf  += hp[b] / pcd;
      loss += (hn[b] / ncd) * cdf;
    }
    out[0] = loss;
  }
}

extern "C" void kernel_launch(void* const* d_in, const int* in_sizes, int n_in,
                              void* d_out, int out_size, void* d_ws, size_t ws_size,
                              hipStream_t stream) {
  const float* x1 = (const float*)d_in[0];
  const float* x2 = (const float*)d_in[1];
  const float* t1 = (const float*)d_in[2];
  const float* t2 = (const float*)d_in[3];
  float* out = (float*)d_out;

  float* ghist = (float*)d_ws;
  unsigned int* gcnt = (unsigned int*)((char*)d_ws + (size_t)NCOPY*2*NSTEPS*sizeof(float));

  hipMemsetAsync(d_ws, 0, (size_t)NCOPY*2*NSTEPS*sizeof(float) + sizeof(unsigned int), stream);
  hist_kernel<<<TBLOCKS, 256, 0, stream>>>(x1, x2, t1, t2, ghist, gcnt);
  finalize_kernel<<<1, 256, 0, stream>>>(ghist, gcnt, out);
}

// Round 3
// 141.314 us; speedup vs baseline: 2.7474x; 1.0131x over previous
//
#include <hip/hip_runtime.h>

#define N_EMB   8192
#define D_EMB   128
#define NSTEPS  201
#define STEPF   0.01f
#define NB      128                  // 8192 / 64 tiles per dim
#define TBLOCKS (NB*(NB+1)/2)        // 8256 upper-tri tiles incl. diagonal
#define NCOPY   64                   // replicated global histograms
#define NHIST   8                    // per-half-wave LDS histogram copies

typedef __attribute__((ext_vector_type(8))) short bf16x8;
typedef __attribute__((ext_vector_type(4))) float f32x4;

// packed per-bin accumulator: (count << 21) | round(frac * 1024)
#define FRAC_SCALE 1024.0f
#define CNT_SHIFT  21
#define FRAC_MASK  ((1u << CNT_SHIFT) - 1u)

__device__ __forceinline__ unsigned short f2bf(float f) {
  unsigned int u = __builtin_bit_cast(unsigned int, f);
  u = (u + 0x7fffu + ((u >> 16) & 1u)) >> 16;   // RNE fp32 -> bf16
  return (unsigned short)u;
}

// ---- pre-pass: fp32 row-major -> bf16 MFMA-fragment-tiled layout ----
// chunk index ((R*4 + K)*64 + kg*16 + fr), R=row/16, K=col/32, fr=row%16, kg=(col%32)/8
// so a 16x16x32 fragment load is one coalesced dwordx4 at base + lane*16B.
__global__ __launch_bounds__(256) void convert_kernel(
    const float* __restrict__ x1, const float* __restrict__ x2,
    unsigned short* __restrict__ x1b, unsigned short* __restrict__ x2b)
{
  int t = blockIdx.x * 256 + threadIdx.x;          // 0 .. 2*131072-1
  const float*    src = (t < 131072) ? x1  : x2;
  unsigned short* dst = (t < 131072) ? x1b : x2b;
  int tt  = t & 131071;
  int r   = tt >> 4;
  int c16 = tt & 15;
  const float4* g = reinterpret_cast<const float4*>(src + ((size_t)r << 7) + c16*8);
  float4 v0 = g[0], v1 = g[1];
  int R = r >> 4, fr = r & 15, K = c16 >> 2, kg = c16 & 3;
  size_t chunk = ((size_t)(R*4 + K) << 6) + (size_t)(kg*16 + fr);
  uint4 p;
  p.x = f2bf(v0.x) | ((unsigned int)f2bf(v0.y) << 16);
  p.y = f2bf(v0.z) | ((unsigned int)f2bf(v0.w) << 16);
  p.z = f2bf(v1.x) | ((unsigned int)f2bf(v1.y) << 16);
  p.w = f2bf(v1.z) | ((unsigned int)f2bf(v1.w) << 16);
  *reinterpret_cast<uint4*>(dst + chunk*8) = p;
}

__global__ __launch_bounds__(256, 6) void hist_kernel(
    const unsigned short* __restrict__ x1b, const unsigned short* __restrict__ x2b,
    const float* __restrict__ t1, const float* __restrict__ t2,
    float* __restrict__ ghist, unsigned int* __restrict__ gcnt)
{
  __shared__ float sT1[64], sT2[64];
  __shared__ unsigned int whist[NHIST][2][NSTEPS];   // per-half-wave {pos,neg} packed u32
  __shared__ unsigned int blk_pos;

  const int tid = threadIdx.x;

  // ---- linear block id -> (bi, bj) with bi <= bj (upper triangle) ----
  int t   = (int)blockIdx.x;
  int rem = TBLOCKS - 1 - t;
  int r   = (int)((sqrtf(8.0f*(float)rem + 1.0f) - 1.0f) * 0.5f);
  while ((r+1)*(r+2)/2 <= rem) ++r;
  while (r*(r+1)/2 > rem) --r;
  const int bi  = NB - 1 - r;
  const int bj  = NB - 1 - (rem - r*(r+1)/2);
  const int gi0 = bi*64, gj0 = bj*64;

  // ---- zero histograms / counter, stage targets ----
  for (int b = tid; b < NHIST*2*NSTEPS; b += 256) ((unsigned int*)whist)[b] = 0u;
  if (tid == 0) blk_pos = 0u;
  if (tid < 64)        sT2[tid]      = t2[gi0 + tid];
  else if (tid < 128)  sT1[tid - 64] = t1[gj0 + (tid - 64)];
  __syncthreads();

  // ---- MFMA: 4 waves, each a 32x32 quadrant; fragments direct from L2 ----
  const int lane = tid & 63;
  const int w    = tid >> 6;
  const int wr   = w >> 1, wc = w & 1;
  const int fr   = lane & 15;
  const int kg   = lane >> 4;

  const int Ra = (gi0 >> 4) + wr*2;   // A row-block (16-row units)
  const int Rb = (gj0 >> 4) + wc*2;   // B row-block

  f32x4 acc00 = {0.f,0.f,0.f,0.f}, acc01 = {0.f,0.f,0.f,0.f};
  f32x4 acc10 = {0.f,0.f,0.f,0.f}, acc11 = {0.f,0.f,0.f,0.f};

#pragma unroll
  for (int ks = 0; ks < 4; ++ks) {
    bf16x8 a0 = *reinterpret_cast<const bf16x8*>(x1b + ((((size_t)Ra    *4 + ks)*64 + lane) << 3));
    bf16x8 a1 = *reinterpret_cast<const bf16x8*>(x1b + ((((size_t)(Ra+1)*4 + ks)*64 + lane) << 3));
    bf16x8 b0 = *reinterpret_cast<const bf16x8*>(x2b + ((((size_t)Rb    *4 + ks)*64 + lane) << 3));
    bf16x8 b1 = *reinterpret_cast<const bf16x8*>(x2b + ((((size_t)(Rb+1)*4 + ks)*64 + lane) << 3));
    acc00 = __builtin_amdgcn_mfma_f32_16x16x32_bf16(a0, b0, acc00, 0, 0, 0);
    acc01 = __builtin_amdgcn_mfma_f32_16x16x32_bf16(a0, b1, acc01, 0, 0, 0);
    acc10 = __builtin_amdgcn_mfma_f32_16x16x32_bf16(a1, b0, acc10, 0, 0, 0);
    acc11 = __builtin_amdgcn_mfma_f32_16x16x32_bf16(a1, b1, acc11, 0, 0, 0);
  }

  // ---- soft binning: ONE packed u32 LDS atomic per pair ----
  // C/D layout (verified m89/m91): col = lane&15, row = (lane>>4)*4 + reg
  const int hw = (w << 1) | (lane >> 5);
  unsigned int* hp = whist[hw][0];
  unsigned int* hn = whist[hw][1];
  const int rbase = kg * 4;

  auto binTile = [&](const f32x4& acc, int tm, int tn) {
    int lj = wc*32 + tn*16 + fr;
    int gj = gj0 + lj;
    float t1v = sT1[lj];
#pragma unroll
    for (int rr = 0; rr < 4; ++rr) {
      int li = wr*32 + tm*16 + rbase + rr;
      int gi = gi0 + li;
      if (gj > gi) {                       // strictly-upper pairs only
        float s   = acc[rr];
        float t2v = sT2[li];
        bool  pos = (t2v * t1v) > 0.0f;
        float u   = (s + 1.0f) * 100.0f;   // (s+1)/step
        int   idx = (int)floorf(u);
        idx = idx < 0 ? 0 : (idx > NSTEPS-1 ? NSTEPS-1 : idx);
        float delta = (float)idx * STEPF - 1.0f;
        float frac  = (s - delta) * 100.0f;
        frac = fminf(fmaxf(frac, 0.0f), 1.0f);
        unsigned int pk = (1u << CNT_SHIFT) | (unsigned int)(frac * FRAC_SCALE + 0.5f);
        atomicAdd(pos ? &hp[idx] : &hn[idx], pk);
      }
    }
  };
  binTile(acc00, 0, 0); binTile(acc01, 0, 1);
  binTile(acc10, 1, 0); binTile(acc11, 1, 1);

  __syncthreads();

  // ---- unpack + flush block histogram into one of NCOPY global copies ----
  // h[b] = cnt[b] - fr[b] + fr[b-1]  (b<200);  h[200] = cnt[200] + fr[199]
  float* gh = ghist + (size_t)(blockIdx.x & (NCOPY-1)) * (2*NSTEPS);
  if (tid < NSTEPS) {
    const int b = tid;
    unsigned int cp = 0, cn = 0;
    float fp = 0.f, fn = 0.f, fpm1 = 0.f, fnm1 = 0.f;
#pragma unroll
    for (int ww = 0; ww < NHIST; ++ww) {
      unsigned int vp = whist[ww][0][b], vn = whist[ww][1][b];
      cp += vp >> CNT_SHIFT;  fp += (float)(vp & FRAC_MASK);
      cn += vn >> CNT_SHIFT;  fn += (float)(vn & FRAC_MASK);
      if (b > 0) {
        unsigned int vpm = whist[ww][0][b-1], vnm = whist[ww][1][b-1];
        fpm1 += (float)(vpm & FRAC_MASK);
        fnm1 += (float)(vnm & FRAC_MASK);
      }
    }
    const float inv = 1.0f / FRAC_SCALE;
    float hpv, hnv;
    if (b == NSTEPS-1) {                   // idx_hi clamp: frac stays in bin 200
      hpv = (float)cp + fpm1 * inv;
      hnv = (float)cn + fnm1 * inv;
    } else {
      hpv = (float)cp - fp * inv + fpm1 * inv;
      hnv = (float)cn - fn * inv + fnm1 * inv;
    }
    if (hpv != 0.0f) atomicAdd(&gh[b],          hpv);
    if (hnv != 0.0f) atomicAdd(&gh[NSTEPS + b], hnv);
    if (cp) atomicAdd(&blk_pos, cp);
  }
  __syncthreads();
  if (tid == 0 && blk_pos) atomicAdd(gcnt, blk_pos);
}

__global__ void finalize_kernel(const float* __restrict__ ghist,
                                const unsigned int* __restrict__ gcnt,
                                float* __restrict__ out)
{
  __shared__ float hp[NSTEPS], hn[NSTEPS];
  const int tid = threadIdx.x;
  for (int b = tid; b < NSTEPS; b += 256) {
    float sp = 0.f, sn = 0.f;
    for (int c = 0; c < NCOPY; ++c) {
      sp += ghist[(size_t)c*(2*NSTEPS) + b];
      sn += ghist[(size_t)c*(2*NSTEPS) + NSTEPS + b];
    }
    hp[b] = sp; hn[b] = sn;
  }
  __syncthreads();
  if (tid == 0) {
    const unsigned long long TOT = (unsigned long long)N_EMB * (N_EMB-1) / 2;  // 33550336
    float pc = (float)gcnt[0];
    float nc = (float)(TOT - (unsigned long long)gcnt[0]);
    float pcd = fmaxf(pc, 1.0f), ncd = fmaxf(nc, 1.0f);
    float cdf = 0.f, loss = 0.f;
    for (int b = 0; b < NSTEPS; ++b) {
      cdf  += hp[b] / pcd;
      loss += (hn[b] / ncd) * cdf;
    }
    out[0] = loss;
  }
}

extern "C" void kernel_launch(void* const* d_in, const int* in_sizes, int n_in,
                              void* d_out, int out_size, void* d_ws, size_t ws_size,
                              hipStream_t stream) {
  const float* x1 = (const float*)d_in[0];
  const float* x2 = (const float*)d_in[1];
  const float* t1 = (const float*)d_in[2];
  const float* t2 = (const float*)d_in[3];
  float* out = (float*)d_out;

  const size_t BF_BYTES = (size_t)N_EMB * D_EMB * sizeof(unsigned short);  // 2 MB each
  unsigned short* x1b = (unsigned short*)d_ws;
  unsigned short* x2b = (unsigned short*)((char*)d_ws + BF_BYTES);
  float* ghist = (float*)((char*)d_ws + 2*BF_BYTES);
  unsigned int* gcnt = (unsigned int*)((char*)d_ws + 2*BF_BYTES + (size_t)NCOPY*2*NSTEPS*sizeof(float));

  hipMemsetAsync((char*)d_ws + 2*BF_BYTES, 0,
                 (size_t)NCOPY*2*NSTEPS*sizeof(float) + sizeof(unsigned int), stream);
  convert_kernel<<<(2*N_EMB*D_EMB/8 + 255)/256, 256, 0, stream>>>(x1, x2, x1b, x2b);
  hist_kernel<<<TBLOCKS, 256, 0, stream>>>(x1b, x2b, t1, t2, ghist, gcnt);
  finalize_kernel<<<1, 256, 0, stream>>>(ghist, gcnt, out);
}

// Round 4
// 108.775 us; speedup vs baseline: 3.5692x; 1.2991x over previous
//
#include <hip/hip_runtime.h>

#define N_EMB   8192
#define D_EMB   128
#define NSTEPS  201
#define NB      128                  // 8192 / 64 tiles per dim
#define TBLOCKS (NB*(NB+1)/2)        // 8256 upper-tri tiles incl. diagonal
#define NCOPY   64                   // replicated global pos-histograms
#define NHIST   16                   // per-quarter-wave LDS histogram copies

typedef __attribute__((ext_vector_type(8))) short bf16x8;
typedef __attribute__((ext_vector_type(4))) float f32x4;

// packed per-bin accumulator: (count << 21) | fq, fq = round(frac*1024)
#define CNT_SHIFT  21
#define FRAC_MASK  ((1u << CNT_SHIFT) - 1u)

__device__ __forceinline__ unsigned short f2bf(float f) {
  unsigned int u = __builtin_bit_cast(unsigned int, f);
  u = (u + 0x7fffu + ((u >> 16) & 1u)) >> 16;   // RNE fp32 -> bf16
  return (unsigned short)u;
}

// ---- tile id -> (bi, bj), bi <= bj ----
__device__ __forceinline__ void tile_coords(int t, int& bi, int& bj) {
  int rem = TBLOCKS - 1 - t;
  int r   = (int)((sqrtf(8.0f*(float)rem + 1.0f) - 1.0f) * 0.5f);
  while ((r+1)*(r+2)/2 <= rem) ++r;
  while (r*(r+1)/2 > rem) --r;
  bi = NB - 1 - r;
  bj = NB - 1 - (rem - r*(r+1)/2);
}

// ---- pre-pass: fp32 row-major -> bf16 MFMA-fragment-tiled layout ----
__global__ __launch_bounds__(256) void convert_kernel(
    const float* __restrict__ x1, const float* __restrict__ x2,
    unsigned short* __restrict__ x1b, unsigned short* __restrict__ x2b)
{
  int t = blockIdx.x * 256 + threadIdx.x;
  const float*    src = (t < 131072) ? x1  : x2;
  unsigned short* dst = (t < 131072) ? x1b : x2b;
  int tt  = t & 131071;
  int r   = tt >> 4;
  int c16 = tt & 15;
  const float4* g = reinterpret_cast<const float4*>(src + ((size_t)r << 7) + c16*8);
  float4 v0 = g[0], v1 = g[1];
  int R = r >> 4, fr = r & 15, K = c16 >> 2, kg = c16 & 3;
  size_t chunk = ((size_t)(R*4 + K) << 6) + (size_t)(kg*16 + fr);
  uint4 p;
  p.x = f2bf(v0.x) | ((unsigned int)f2bf(v0.y) << 16);
  p.y = f2bf(v0.z) | ((unsigned int)f2bf(v0.w) << 16);
  p.z = f2bf(v1.x) | ((unsigned int)f2bf(v1.y) << 16);
  p.w = f2bf(v1.z) | ((unsigned int)f2bf(v1.w) << 16);
  *reinterpret_cast<uint4*>(dst + chunk*8) = p;
}

// ============ pass B: positive-pair histogram (packed LDS atomics) ============
__global__ __launch_bounds__(256, 6) void poshist_kernel(
    const unsigned short* __restrict__ x1b, const unsigned short* __restrict__ x2b,
    const float* __restrict__ t1, const float* __restrict__ t2,
    float* __restrict__ ghist)
{
  __shared__ float sT1[64], sT2[64];
  __shared__ unsigned int whist[NHIST][NSTEPS];

  const int tid = threadIdx.x;
  int bi, bj; tile_coords((int)blockIdx.x, bi, bj);
  const int gi0 = bi*64, gj0 = bj*64;
  const bool full = (bi != bj);

  for (int b = tid; b < NHIST*NSTEPS; b += 256) ((unsigned int*)whist)[b] = 0u;
  if (tid < 64)        sT2[tid]      = t2[gi0 + tid];
  else if (tid < 128)  sT1[tid - 64] = t1[gj0 + (tid - 64)];
  __syncthreads();

  const int lane = tid & 63;
  const int w    = tid >> 6;
  const int wr   = w >> 1, wc = w & 1;
  const int fr   = lane & 15;
  const int kg   = lane >> 4;
  const int Ra = (gi0 >> 4) + wr*2;
  const int Rb = (gj0 >> 4) + wc*2;

  f32x4 acc00 = {0.f,0.f,0.f,0.f}, acc01 = {0.f,0.f,0.f,0.f};
  f32x4 acc10 = {0.f,0.f,0.f,0.f}, acc11 = {0.f,0.f,0.f,0.f};
#pragma unroll
  for (int ks = 0; ks < 4; ++ks) {
    bf16x8 a0 = *reinterpret_cast<const bf16x8*>(x1b + ((((size_t)Ra    *4 + ks)*64 + lane) << 3));
    bf16x8 a1 = *reinterpret_cast<const bf16x8*>(x1b + ((((size_t)(Ra+1)*4 + ks)*64 + lane) << 3));
    bf16x8 b0 = *reinterpret_cast<const bf16x8*>(x2b + ((((size_t)Rb    *4 + ks)*64 + lane) << 3));
    bf16x8 b1 = *reinterpret_cast<const bf16x8*>(x2b + ((((size_t)(Rb+1)*4 + ks)*64 + lane) << 3));
    acc00 = __builtin_amdgcn_mfma_f32_16x16x32_bf16(a0, b0, acc00, 0, 0, 0);
    acc01 = __builtin_amdgcn_mfma_f32_16x16x32_bf16(a0, b1, acc01, 0, 0, 0);
    acc10 = __builtin_amdgcn_mfma_f32_16x16x32_bf16(a1, b0, acc10, 0, 0, 0);
    acc11 = __builtin_amdgcn_mfma_f32_16x16x32_bf16(a1, b1, acc11, 0, 0, 0);
  }

  // C/D layout (m89/m91): col = lane&15, row = (lane>>4)*4 + reg
  const int hq = (w << 2) | (lane >> 4);      // quarter-wave copy
  unsigned int* wh = whist[hq];
  const int rbase = kg * 4;

  auto binTile = [&](const f32x4& acc, int tm, int tn) {
    int lj = wc*32 + tn*16 + fr;
    int gj = gj0 + lj;
    float t1v = sT1[lj];
#pragma unroll
    for (int rr = 0; rr < 4; ++rr) {
      int li = wr*32 + tm*16 + rbase + rr;
      int gi = gi0 + li;
      float s   = acc[rr];
      float t2v = sT2[li];
      bool take = (full || gj > gi) && (t2v * t1v > 0.0f);
      // fixed-point soft binning: iu = round((s+1)*100*1024)
      float u  = fmaf(s, 102400.0f, 102400.5f);
      int   iu = (int)u;
      int  idx = iu >> 10;
      idx = idx < 0 ? 0 : (idx > NSTEPS-1 ? NSTEPS-1 : idx);
      unsigned int pk = (1u << CNT_SHIFT) | (unsigned int)(iu & 1023);
      if (take) atomicAdd(&wh[idx], pk);
    }
  };
  binTile(acc00, 0, 0); binTile(acc01, 0, 1);
  binTile(acc10, 1, 0); binTile(acc11, 1, 1);
  __syncthreads();

  // unpack + flush:  h[b] = cnt[b] - fr[b]/1024 + fr[b-1]/1024 ; h[200] = cnt[200] + fr[199]/1024
  float* gh = ghist + (size_t)(blockIdx.x & (NCOPY-1)) * NSTEPS;
  if (tid < NSTEPS) {
    const int b = tid;
    unsigned int cp = 0; float fp = 0.f, fpm1 = 0.f;
#pragma unroll
    for (int ww = 0; ww < NHIST; ++ww) {
      unsigned int vp = whist[ww][b];
      cp += vp >> CNT_SHIFT;  fp += (float)(vp & FRAC_MASK);
      if (b > 0) fpm1 += (float)(whist[ww][b-1] & FRAC_MASK);
    }
    const float inv = 1.0f / 1024.0f;
    float hpv = (b == NSTEPS-1) ? ((float)cp + fpm1 * inv)
                                : ((float)cp - fp * inv + fpm1 * inv);
    if (hpv != 0.0f) atomicAdd(&gh[b], hpv);
  }
}

// ============ pass C: sum copies, cumsum, build (C, dC) interp table ============
__global__ void cdf_kernel(const float* __restrict__ ghist,
                           float2* __restrict__ pd, float* __restrict__ np_out)
{
  __shared__ float h[NSTEPS];
  __shared__ float C[NSTEPS + 1];
  const int tid = threadIdx.x;
  if (tid < NSTEPS) {
    float s = 0.f;
    for (int c = 0; c < NCOPY; ++c) s += ghist[(size_t)c*NSTEPS + tid];
    h[tid] = s;
  }
  __syncthreads();
  if (tid == 0) {
    float run = 0.f;
    for (int b = 0; b < NSTEPS; ++b) { run += h[b]; C[b] = run; }
    C[NSTEPS] = run;                   // pad: C[201] = C[200]
    np_out[0] = run;                   // Np = sum of pos weights
  }
  __syncthreads();
  if (tid < NSTEPS) {
    float np = C[NSTEPS - 1];
    float inv = 1.0f / fmaxf(np, 1.0f);
    float cv = C[tid] * inv;
    float dv = (C[tid + 1] - C[tid]) * inv;
    pd[tid] = make_float2(cv, dv);
  }
}

// ============ pass D: negative pairs interpolate pos-CDF, register accumulate ====
__global__ __launch_bounds__(256, 8) void neginterp_kernel(
    const unsigned short* __restrict__ x1b, const unsigned short* __restrict__ x2b,
    const float* __restrict__ t1, const float* __restrict__ t2,
    const float2* __restrict__ pd, float* __restrict__ accbuf)
{
  __shared__ float sT1[64], sT2[64];
  __shared__ float2 sPD[NSTEPS];
  __shared__ float wsum[4];

  const int tid = threadIdx.x;
  int bi, bj; tile_coords((int)blockIdx.x, bi, bj);
  const int gi0 = bi*64, gj0 = bj*64;
  const bool full = (bi != bj);

  if (tid < NSTEPS) sPD[tid] = pd[tid];
  if (tid < 64)        sT2[tid]      = t2[gi0 + tid];
  else if (tid < 128)  sT1[tid - 64] = t1[gj0 + (tid - 64)];
  __syncthreads();

  const int lane = tid & 63;
  const int w    = tid >> 6;
  const int wr   = w >> 1, wc = w & 1;
  const int fr   = lane & 15;
  const int kg   = lane >> 4;
  const int Ra = (gi0 >> 4) + wr*2;
  const int Rb = (gj0 >> 4) + wc*2;

  f32x4 acc00 = {0.f,0.f,0.f,0.f}, acc01 = {0.f,0.f,0.f,0.f};
  f32x4 acc10 = {0.f,0.f,0.f,0.f}, acc11 = {0.f,0.f,0.f,0.f};
#pragma unroll
  for (int ks = 0; ks < 4; ++ks) {
    bf16x8 a0 = *reinterpret_cast<const bf16x8*>(x1b + ((((size_t)Ra    *4 + ks)*64 + lane) << 3));
    bf16x8 a1 = *reinterpret_cast<const bf16x8*>(x1b + ((((size_t)(Ra+1)*4 + ks)*64 + lane) << 3));
    bf16x8 b0 = *reinterpret_cast<const bf16x8*>(x2b + ((((size_t)Rb    *4 + ks)*64 + lane) << 3));
    bf16x8 b1 = *reinterpret_cast<const bf16x8*>(x2b + ((((size_t)Rb+1)*4*64) + ((size_t)ks*64 + lane) * 1 * 8 + ((size_t)Rb*4*64*0) ));
    // (rewritten below for clarity)
    b1 = *reinterpret_cast<const bf16x8*>(x2b + ((((size_t)(Rb+1)*4 + ks)*64 + lane) << 3));
    acc00 = __builtin_amdgcn_mfma_f32_16x16x32_bf16(a0, b0, acc00, 0, 0, 0);
    acc01 = __builtin_amdgcn_mfma_f32_16x16x32_bf16(a0, b1, acc01, 0, 0, 0);
    acc10 = __builtin_amdgcn_mfma_f32_16x16x32_bf16(a1, b0, acc10, 0, 0, 0);
    acc11 = __builtin_amdgcn_mfma_f32_16x16x32_bf16(a1, b1, acc11, 0, 0, 0);
  }

  const int rbase = kg * 4;
  float acc = 0.0f;

  auto evalTile = [&](const f32x4& a, int tm, int tn) {
    int lj = wc*32 + tn*16 + fr;
    int gj = gj0 + lj;
    float t1v = sT1[lj];
#pragma unroll
    for (int rr = 0; rr < 4; ++rr) {
      int li = wr*32 + tm*16 + rbase + rr;
      int gi = gi0 + li;
      float s   = a[rr];
      float t2v = sT2[li];
      bool take = (full || gj > gi) && (t2v * t1v <= 0.0f);   // negative pairs
      float u   = fmaf(s, 100.0f, 100.0f);
      int  idx  = (int)u;
      idx = idx < 0 ? 0 : (idx > NSTEPS-1 ? NSTEPS-1 : idx);
      float frac = u - (float)idx;
      frac = fminf(fmaxf(frac, 0.0f), 1.0f);
      float2 pdv = sPD[idx];
      float contrib = fmaf(frac, pdv.y, pdv.x);
      acc += take ? contrib : 0.0f;
    }
  };
  evalTile(acc00, 0, 0); evalTile(acc01, 0, 1);
  evalTile(acc10, 1, 0); evalTile(acc11, 1, 1);

  // block reduction
#pragma unroll
  for (int off = 32; off > 0; off >>= 1) acc += __shfl_xor(acc, off, 64);
  if (lane == 0) wsum[w] = acc;
  __syncthreads();
  if (tid == 0) {
    float s = wsum[0] + wsum[1] + wsum[2] + wsum[3];
    atomicAdd(&accbuf[blockIdx.x & (NCOPY-1)], s);
  }
}

// ============ finalize ============
__global__ void finalize_kernel(const float* __restrict__ accbuf,
                                const float* __restrict__ np_in,
                                float* __restrict__ out)
{
  if (threadIdx.x == 0) {
    float s = 0.f;
    for (int c = 0; c < NCOPY; ++c) s += accbuf[c];
    const float TOT = 33550336.0f;            // N*(N-1)/2
    float nn = fmaxf(TOT - np_in[0], 1.0f);
    out[0] = s / nn;
  }
}

extern "C" void kernel_launch(void* const* d_in, const int* in_sizes, int n_in,
                              void* d_out, int out_size, void* d_ws, size_t ws_size,
                              hipStream_t stream) {
  const float* x1 = (const float*)d_in[0];
  const float* x2 = (const float*)d_in[1];
  const float* t1 = (const float*)d_in[2];
  const float* t2 = (const float*)d_in[3];
  float* out = (float*)d_out;

  const size_t BF_BYTES = (size_t)N_EMB * D_EMB * sizeof(unsigned short);  // 2 MB each
  char* p = (char*)d_ws;
  unsigned short* x1b   = (unsigned short*)p;                 p += BF_BYTES;
  unsigned short* x2b   = (unsigned short*)p;                 p += BF_BYTES;
  float*          ghist = (float*)p;                          p += (size_t)NCOPY*NSTEPS*sizeof(float);
  float*          accb  = (float*)p;                          p += (size_t)NCOPY*sizeof(float);
  float2*         pd    = (float2*)p;                         p += (size_t)NSTEPS*sizeof(float2);
  float*          np    = (float*)p;

  // zero ghist + accbuf each call (deterministic)
  hipMemsetAsync(ghist, 0, (size_t)NCOPY*NSTEPS*sizeof(float) + (size_t)NCOPY*sizeof(float), stream);

  convert_kernel<<<(2*N_EMB*D_EMB/8 + 255)/256, 256, 0, stream>>>(x1, x2, x1b, x2b);
  poshist_kernel<<<TBLOCKS, 256, 0, stream>>>(x1b, x2b, t1, t2, ghist);
  cdf_kernel<<<1, 256, 0, stream>>>(ghist, pd, np);
  neginterp_kernel<<<TBLOCKS, 256, 0, stream>>>(x1b, x2b, t1, t2, pd, accb);
  finalize_kernel<<<1, 64, 0, stream>>>(accb, np, out);
}

// Round 5
// 80.076 us; speedup vs baseline: 4.8484x; 1.3584x over previous
//
#include <hip/hip_runtime.h>

#define N_EMB   8192
#define D_EMB   128
#define NSTEPS  201
#define NB      128                  // 8192 / 64 tiles per dim
#define TBLOCKS (NB*(NB+1)/2)        // 8256 upper-tri tiles incl. diagonal
#define NCOPY   64                   // replicated global pos-histograms
#define NHIST   16                   // per-quarter-wave LDS histogram copies
#define PGRID   2048                 // persistent grid (8 blocks/CU)

typedef __attribute__((ext_vector_type(8))) short bf16x8;
typedef __attribute__((ext_vector_type(4))) float f32x4;

// packed per-bin accumulator: (count << 21) | fq, fq = round(frac*1024)
#define CNT_SHIFT  21
#define FRAC_MASK  ((1u << CNT_SHIFT) - 1u)

__device__ __forceinline__ unsigned short f2bf(float f) {
  unsigned int u = __builtin_bit_cast(unsigned int, f);
  u = (u + 0x7fffu + ((u >> 16) & 1u)) >> 16;   // RNE fp32 -> bf16
  return (unsigned short)u;
}

// ---- tile id -> (bi, bj), bi <= bj ----
__device__ __forceinline__ void tile_coords(int t, int& bi, int& bj) {
  int rem = TBLOCKS - 1 - t;
  int r   = (int)((sqrtf(8.0f*(float)rem + 1.0f) - 1.0f) * 0.5f);
  while ((r+1)*(r+2)/2 <= rem) ++r;
  while (r*(r+1)/2 > rem) --r;
  bi = NB - 1 - r;
  bj = NB - 1 - (rem - r*(r+1)/2);
}

// ---- pre-pass: fp32 row-major -> bf16 MFMA-fragment-tiled layout ----
__global__ __launch_bounds__(256) void convert_kernel(
    const float* __restrict__ x1, const float* __restrict__ x2,
    unsigned short* __restrict__ x1b, unsigned short* __restrict__ x2b)
{
  int t = blockIdx.x * 256 + threadIdx.x;
  const float*    src = (t < 131072) ? x1  : x2;
  unsigned short* dst = (t < 131072) ? x1b : x2b;
  int tt  = t & 131071;
  int r   = tt >> 4;
  int c16 = tt & 15;
  const float4* g = reinterpret_cast<const float4*>(src + ((size_t)r << 7) + c16*8);
  float4 v0 = g[0], v1 = g[1];
  int R = r >> 4, fr = r & 15, K = c16 >> 2, kg = c16 & 3;
  size_t chunk = ((size_t)(R*4 + K) << 6) + (size_t)(kg*16 + fr);
  uint4 p;
  p.x = f2bf(v0.x) | ((unsigned int)f2bf(v0.y) << 16);
  p.y = f2bf(v0.z) | ((unsigned int)f2bf(v0.w) << 16);
  p.z = f2bf(v1.x) | ((unsigned int)f2bf(v1.y) << 16);
  p.w = f2bf(v1.z) | ((unsigned int)f2bf(v1.w) << 16);
  *reinterpret_cast<uint4*>(dst + chunk*8) = p;
}

// ============ pass B: positive-pair histogram (persistent blocks) ============
__global__ __launch_bounds__(256, 8) void poshist_kernel(
    const unsigned short* __restrict__ x1b, const unsigned short* __restrict__ x2b,
    const float* __restrict__ t1, const float* __restrict__ t2,
    float* __restrict__ ghist)
{
  __shared__ float sT1[64], sT2[64];
  __shared__ unsigned int whist[NHIST][NSTEPS];

  const int tid = threadIdx.x;
  for (int b = tid; b < NHIST*NSTEPS; b += 256) ((unsigned int*)whist)[b] = 0u;

  const int lane = tid & 63;
  const int w    = tid >> 6;
  const int wr   = w >> 1, wc = w & 1;
  const int fr   = lane & 15;
  const int kg   = lane >> 4;
  const int rbase = kg * 4;
  unsigned int* wh = whist[(w << 2) | kg];

  const int t0  = (int)(((unsigned)blockIdx.x       * (unsigned)TBLOCKS) >> 11);
  const int t1e = (int)((((unsigned)blockIdx.x + 1u) * (unsigned)TBLOCKS) >> 11);

  for (int t = t0; t < t1e; ++t) {
    int bi, bj; tile_coords(t, bi, bj);
    const int gi0 = bi*64, gj0 = bj*64;
    const bool full = (bi != bj);

    __syncthreads();                         // previous tile's epilogue done with sT
    if (tid < 64)        sT2[tid]      = t2[gi0 + tid];
    else if (tid < 128)  sT1[tid - 64] = t1[gj0 + (tid - 64)];
    __syncthreads();

    const int Ra = (gi0 >> 4) + wr*2;
    const int Rb = (gj0 >> 4) + wc*2;
    f32x4 acc00 = {0.f,0.f,0.f,0.f}, acc01 = {0.f,0.f,0.f,0.f};
    f32x4 acc10 = {0.f,0.f,0.f,0.f}, acc11 = {0.f,0.f,0.f,0.f};
#pragma unroll
    for (int ks = 0; ks < 4; ++ks) {
      bf16x8 a0 = *reinterpret_cast<const bf16x8*>(x1b + ((((size_t)Ra    *4 + ks)*64 + lane) << 3));
      bf16x8 a1 = *reinterpret_cast<const bf16x8*>(x1b + ((((size_t)(Ra+1)*4 + ks)*64 + lane) << 3));
      bf16x8 b0 = *reinterpret_cast<const bf16x8*>(x2b + ((((size_t)Rb    *4 + ks)*64 + lane) << 3));
      bf16x8 b1 = *reinterpret_cast<const bf16x8*>(x2b + ((((size_t)(Rb+1)*4 + ks)*64 + lane) << 3));
      acc00 = __builtin_amdgcn_mfma_f32_16x16x32_bf16(a0, b0, acc00, 0, 0, 0);
      acc01 = __builtin_amdgcn_mfma_f32_16x16x32_bf16(a0, b1, acc01, 0, 0, 0);
      acc10 = __builtin_amdgcn_mfma_f32_16x16x32_bf16(a1, b0, acc10, 0, 0, 0);
      acc11 = __builtin_amdgcn_mfma_f32_16x16x32_bf16(a1, b1, acc11, 0, 0, 0);
    }

    // hoist target reads (static indices -> registers)
    float T2v[2][4], T1v[2];
#pragma unroll
    for (int tm = 0; tm < 2; ++tm)
#pragma unroll
      for (int rr = 0; rr < 4; ++rr) T2v[tm][rr] = sT2[wr*32 + tm*16 + rbase + rr];
    T1v[0] = sT1[wc*32 + fr];
    T1v[1] = sT1[wc*32 + 16 + fr];

    // C/D layout (m89/m91): col = lane&15, row = (lane>>4)*4 + reg
    auto dep = [&](const f32x4& a, int tm, int tn) {
      const int lj = wc*32 + tn*16 + fr;
      const float t1v = T1v[tn];
#pragma unroll
      for (int rr = 0; rr < 4; ++rr) {
        const int li = wr*32 + tm*16 + rbase + rr;
        bool take = (full || (lj > li)) && (T2v[tm][rr] * t1v > 0.0f);
        float uu = fmaf(a[rr], 102400.0f, 102400.5f);
        int   iu = (int)uu;
        int  idx = iu >> 10;
        idx = idx < 0 ? 0 : (idx > NSTEPS-1 ? NSTEPS-1 : idx);
        unsigned int pk = (1u << CNT_SHIFT) | (unsigned int)(iu & 1023);
        if (take) atomicAdd(&wh[idx], pk);
      }
    };
    dep(acc00, 0, 0); dep(acc01, 0, 1);
    dep(acc10, 1, 0); dep(acc11, 1, 1);
  }
  __syncthreads();

  // unpack + flush once:  h[b] = cnt[b] - fr[b]/1024 + fr[b-1]/1024 ; h[200] = cnt[200] + fr[199]/1024
  float* gh = ghist + (size_t)(blockIdx.x & (NCOPY-1)) * NSTEPS;
  if (tid < NSTEPS) {
    const int b = tid;
    unsigned int cp = 0; float fp = 0.f, fpm1 = 0.f;
#pragma unroll
    for (int ww = 0; ww < NHIST; ++ww) {
      unsigned int vp = whist[ww][b];
      cp += vp >> CNT_SHIFT;  fp += (float)(vp & FRAC_MASK);
      if (b > 0) fpm1 += (float)(whist[ww][b-1] & FRAC_MASK);
    }
    const float inv = 1.0f / 1024.0f;
    float hpv = (b == NSTEPS-1) ? ((float)cp + fpm1 * inv)
                                : ((float)cp - fp * inv + fpm1 * inv);
    if (hpv != 0.0f) atomicAdd(&gh[b], hpv);
  }
}

// ====== pass C: sum copies, cumsum, build affine interp table (alpha, beta) ======
// contrib(s in bin b) = C[b]/Np + ((s+1)*100 - b)*dC[b]/Np = alpha[b] + s*beta[b]
__global__ void cdf_kernel(const float* __restrict__ ghist,
                           float2* __restrict__ pd, float* __restrict__ np_out)
{
  __shared__ float h[NSTEPS];
  __shared__ float C[NSTEPS + 1];
  const int tid = threadIdx.x;
  if (tid < NSTEPS) {
    float s = 0.f;
    for (int c = 0; c < NCOPY; ++c) s += ghist[(size_t)c*NSTEPS + tid];
    h[tid] = s;
  }
  __syncthreads();
  if (tid == 0) {
    float run = 0.f;
    for (int b = 0; b < NSTEPS; ++b) { run += h[b]; C[b] = run; }
    C[NSTEPS] = run;                   // pad: d[200] = 0
    np_out[0] = run;                   // Np = pos-pair count (weights telescope to 1)
  }
  __syncthreads();
  if (tid < NSTEPS) {
    float np  = C[NSTEPS - 1];
    float inv = 1.0f / fmaxf(np, 1.0f);
    float d   = (C[tid + 1] - C[tid]) * inv;
    float cv  = C[tid] * inv;
    float alpha = fmaf((float)(100 - tid), d, cv);
    float beta  = 100.0f * d;
    pd[tid] = make_float2(alpha, beta);
  }
}

// ====== pass D: negative pairs interpolate pos-CDF (persistent, register acc) ======
__global__ __launch_bounds__(256, 8) void neginterp_kernel(
    const unsigned short* __restrict__ x1b, const unsigned short* __restrict__ x2b,
    const float* __restrict__ t1, const float* __restrict__ t2,
    const float2* __restrict__ pd, float* __restrict__ accbuf)
{
  __shared__ float sT1[64], sT2[64];
  __shared__ float2 sPD[NSTEPS];
  __shared__ float wsum[4];

  const int tid = threadIdx.x;
  if (tid < NSTEPS) sPD[tid] = pd[tid];

  const int lane = tid & 63;
  const int w    = tid >> 6;
  const int wr   = w >> 1, wc = w & 1;
  const int fr   = lane & 15;
  const int kg   = lane >> 4;
  const int rbase = kg * 4;

  const int t0  = (int)(((unsigned)blockIdx.x       * (unsigned)TBLOCKS) >> 11);
  const int t1e = (int)((((unsigned)blockIdx.x + 1u) * (unsigned)TBLOCKS) >> 11);

  float acc = 0.0f;

  for (int t = t0; t < t1e; ++t) {
    int bi, bj; tile_coords(t, bi, bj);
    const int gi0 = bi*64, gj0 = bj*64;
    const bool full = (bi != bj);

    __syncthreads();                         // previous epilogue done with sT (also covers sPD stage)
    if (tid < 64)        sT2[tid]      = t2[gi0 + tid];
    else if (tid < 128)  sT1[tid - 64] = t1[gj0 + (tid - 64)];
    __syncthreads();

    const int Ra = (gi0 >> 4) + wr*2;
    const int Rb = (gj0 >> 4) + wc*2;
    f32x4 acc00 = {0.f,0.f,0.f,0.f}, acc01 = {0.f,0.f,0.f,0.f};
    f32x4 acc10 = {0.f,0.f,0.f,0.f}, acc11 = {0.f,0.f,0.f,0.f};
#pragma unroll
    for (int ks = 0; ks < 4; ++ks) {
      bf16x8 a0 = *reinterpret_cast<const bf16x8*>(x1b + ((((size_t)Ra    *4 + ks)*64 + lane) << 3));
      bf16x8 a1 = *reinterpret_cast<const bf16x8*>(x1b + ((((size_t)(Ra+1)*4 + ks)*64 + lane) << 3));
      bf16x8 b0 = *reinterpret_cast<const bf16x8*>(x2b + ((((size_t)Rb    *4 + ks)*64 + lane) << 3));
      bf16x8 b1 = *reinterpret_cast<const bf16x8*>(x2b + ((((size_t)(Rb+1)*4 + ks)*64 + lane) << 3));
      acc00 = __builtin_amdgcn_mfma_f32_16x16x32_bf16(a0, b0, acc00, 0, 0, 0);
      acc01 = __builtin_amdgcn_mfma_f32_16x16x32_bf16(a0, b1, acc01, 0, 0, 0);
      acc10 = __builtin_amdgcn_mfma_f32_16x16x32_bf16(a1, b0, acc10, 0, 0, 0);
      acc11 = __builtin_amdgcn_mfma_f32_16x16x32_bf16(a1, b1, acc11, 0, 0, 0);
    }

    float T2v[2][4], T1v[2];
#pragma unroll
    for (int tm = 0; tm < 2; ++tm)
#pragma unroll
      for (int rr = 0; rr < 4; ++rr) T2v[tm][rr] = sT2[wr*32 + tm*16 + rbase + rr];
    T1v[0] = sT1[wc*32 + fr];
    T1v[1] = sT1[wc*32 + 16 + fr];

    auto evalTile = [&](const f32x4& a, int tm, int tn) {
      const int lj = wc*32 + tn*16 + fr;
      const float t1v = T1v[tn];
#pragma unroll
      for (int rr = 0; rr < 4; ++rr) {
        const int li = wr*32 + tm*16 + rbase + rr;
        float s = a[rr];
        bool take = (full || (lj > li)) && (T2v[tm][rr] * t1v <= 0.0f);
        float uu = fmaf(s, 100.0f, 100.0f);
        int  idx = (int)uu;
        idx = idx < 0 ? 0 : (idx > NSTEPS-1 ? NSTEPS-1 : idx);
        float2 ab = sPD[idx];
        float contrib = fmaf(s, ab.y, ab.x);
        acc += take ? contrib : 0.0f;
      }
    };
    evalTile(acc00, 0, 0); evalTile(acc01, 0, 1);
    evalTile(acc10, 1, 0); evalTile(acc11, 1, 1);
  }

  // block reduction (once)
#pragma unroll
  for (int off = 32; off > 0; off >>= 1) acc += __shfl_xor(acc, off, 64);
  if (lane == 0) wsum[w] = acc;
  __syncthreads();
  if (tid == 0) {
    float s = wsum[0] + wsum[1] + wsum[2] + wsum[3];
    atomicAdd(&accbuf[blockIdx.x & (NCOPY-1)], s);
  }
}

// ============ finalize ============
__global__ void finalize_kernel(const float* __restrict__ accbuf,
                                const float* __restrict__ np_in,
                                float* __restrict__ out)
{
  if (threadIdx.x == 0) {
    float s = 0.f;
    for (int c = 0; c < NCOPY; ++c) s += accbuf[c];
    const float TOT = 33550336.0f;            // N*(N-1)/2
    float nn = fmaxf(TOT - np_in[0], 1.0f);
    out[0] = s / nn;
  }
}

extern "C" void kernel_launch(void* const* d_in, const int* in_sizes, int n_in,
                              void* d_out, int out_size, void* d_ws, size_t ws_size,
                              hipStream_t stream) {
  const float* x1 = (const float*)d_in[0];
  const float* x2 = (const float*)d_in[1];
  const float* t1 = (const float*)d_in[2];
  const float* t2 = (const float*)d_in[3];
  float* out = (float*)d_out;

  const size_t BF_BYTES = (size_t)N_EMB * D_EMB * sizeof(unsigned short);  // 2 MB each
  char* p = (char*)d_ws;
  unsigned short* x1b   = (unsigned short*)p;                 p += BF_BYTES;
  unsigned short* x2b   = (unsigned short*)p;                 p += BF_BYTES;
  float*          ghist = (float*)p;                          p += (size_t)NCOPY*NSTEPS*sizeof(float);
  float*          accb  = (float*)p;                          p += (size_t)NCOPY*sizeof(float);
  float2*         pd    = (float2*)p;                         p += (size_t)NSTEPS*sizeof(float2);
  float*          np    = (float*)p;

  hipMemsetAsync(ghist, 0, (size_t)NCOPY*NSTEPS*sizeof(float) + (size_t)NCOPY*sizeof(float), stream);

  convert_kernel<<<(2*N_EMB*D_EMB/8 + 255)/256, 256, 0, stream>>>(x1, x2, x1b, x2b);
  poshist_kernel<<<PGRID, 256, 0, stream>>>(x1b, x2b, t1, t2, ghist);
  cdf_kernel<<<1, 256, 0, stream>>>(ghist, pd, np);
  neginterp_kernel<<<PGRID, 256, 0, stream>>>(x1b, x2b, t1, t2, pd, accb);
  finalize_kernel<<<1, 64, 0, stream>>>(accb, np, out);
}

// Round 6
// 46.897 us; speedup vs baseline: 8.2787x; 1.7075x over previous
//
#include <hip/hip_runtime.h>

#define N_EMB   8192
#define D_EMB   128
#define NSTEPS  201
#define NB      128                  // 8192 / 64 tiles per dim
#define TBLOCKS (NB*(NB+1)/2)        // 8256 upper-tri tiles incl. diagonal
#define NCOPY   16                   // replicated global histogram copies
#define NHIST   16                   // per-quarter-wave LDS copies (per sign table)
#define PGRID   1536                 // persistent grid (6 blocks/CU, LDS-limited)

typedef __attribute__((ext_vector_type(8))) short bf16x8;
typedef __attribute__((ext_vector_type(4))) float f32x4;

// packed per-bin accumulator: (count << 21) | fq, fq = round(frac*1024)
#define CNT_SHIFT  21
#define FRAC_MASK  ((1u << CNT_SHIFT) - 1u)
#define NZERO      (NCOPY * 2 * NSTEPS)      // floats to zero in ghist

__device__ __forceinline__ unsigned short f2bf(float f) {
  unsigned int u = __builtin_bit_cast(unsigned int, f);
  u = (u + 0x7fffu + ((u >> 16) & 1u)) >> 16;   // RNE fp32 -> bf16
  return (unsigned short)u;
}

// ---- tile id -> (bi, bj), bi <= bj ----
__device__ __forceinline__ void tile_coords(int t, int& bi, int& bj) {
  int rem = TBLOCKS - 1 - t;
  int r   = (int)((sqrtf(8.0f*(float)rem + 1.0f) - 1.0f) * 0.5f);
  while ((r+1)*(r+2)/2 <= rem) ++r;
  while (r*(r+1)/2 > rem) --r;
  bi = NB - 1 - r;
  bj = NB - 1 - (rem - r*(r+1)/2);
}

// ---- pre-pass: fp32 -> bf16 fragment-tiled; also zeroes ghist (no memset) ----
__global__ __launch_bounds__(256) void convert_kernel(
    const float* __restrict__ x1, const float* __restrict__ x2,
    unsigned short* __restrict__ x1b, unsigned short* __restrict__ x2b,
    float* __restrict__ ghist)
{
  int t = blockIdx.x * 256 + threadIdx.x;
  if (t < NZERO) ghist[t] = 0.0f;
  const float*    src = (t < 131072) ? x1  : x2;
  unsigned short* dst = (t < 131072) ? x1b : x2b;
  int tt  = t & 131071;
  int r   = tt >> 4;
  int c16 = tt & 15;
  const float4* g = reinterpret_cast<const float4*>(src + ((size_t)r << 7) + c16*8);
  float4 v0 = g[0], v1 = g[1];
  int R = r >> 4, fr = r & 15, K = c16 >> 2, kg = c16 & 3;
  size_t chunk = ((size_t)(R*4 + K) << 6) + (size_t)(kg*16 + fr);
  uint4 p;
  p.x = f2bf(v0.x) | ((unsigned int)f2bf(v0.y) << 16);
  p.y = f2bf(v0.z) | ((unsigned int)f2bf(v0.w) << 16);
  p.z = f2bf(v1.x) | ((unsigned int)f2bf(v1.y) << 16);
  p.w = f2bf(v1.z) | ((unsigned int)f2bf(v1.w) << 16);
  *reinterpret_cast<uint4*>(dst + chunk*8) = p;
}

// ============ main pass: both histograms, persistent blocks ============
__global__ __launch_bounds__(256, 6) void main_kernel(
    const unsigned short* __restrict__ x1b, const unsigned short* __restrict__ x2b,
    const float* __restrict__ t1, const float* __restrict__ t2,
    float* __restrict__ ghist)
{
  __shared__ unsigned int whist[2][NHIST][NSTEPS];   // [pos/neg][copy][bin]
  __shared__ float sT1[64], sT2[64];

  const int tid = threadIdx.x;
  for (int b = tid; b < 2*NHIST*NSTEPS; b += 256) ((unsigned int*)whist)[b] = 0u;

  const int lane = tid & 63;
  const int w    = tid >> 6;
  const int wr   = w >> 1, wc = w & 1;
  const int fr   = lane & 15;
  const int kg   = lane >> 4;
  const int rbase = kg * 4;
  unsigned int* whP = &whist[0][(w << 2) | kg][0];
  const int NEGOFF = NHIST * NSTEPS;          // element offset pos-table -> neg-table

  const int t0  = (int)blockIdx.x       * TBLOCKS / PGRID;
  const int t1e = ((int)blockIdx.x + 1) * TBLOCKS / PGRID;

  for (int t = t0; t < t1e; ++t) {
    int bi, bj; tile_coords(t, bi, bj);
    const int gi0 = bi*64, gj0 = bj*64;
    const bool full = (bi != bj);

    __syncthreads();                           // prev tile done with sT (covers whist zero on iter 0)
    if (tid < 64)        sT2[tid]      = t2[gi0 + tid];
    else if (tid < 128)  sT1[tid - 64] = t1[gj0 + (tid - 64)];
    __syncthreads();

    const int Ra = (gi0 >> 4) + wr*2;
    const int Rb = (gj0 >> 4) + wc*2;
    f32x4 acc00 = {0.f,0.f,0.f,0.f}, acc01 = {0.f,0.f,0.f,0.f};
    f32x4 acc10 = {0.f,0.f,0.f,0.f}, acc11 = {0.f,0.f,0.f,0.f};
#pragma unroll
    for (int ks = 0; ks < 4; ++ks) {
      bf16x8 a0 = *reinterpret_cast<const bf16x8*>(x1b + ((((size_t)Ra    *4 + ks)*64 + lane) << 3));
      bf16x8 a1 = *reinterpret_cast<const bf16x8*>(x1b + ((((size_t)(Ra+1)*4 + ks)*64 + lane) << 3));
      bf16x8 b0 = *reinterpret_cast<const bf16x8*>(x2b + ((((size_t)Rb    *4 + ks)*64 + lane) << 3));
      bf16x8 b1 = *reinterpret_cast<const bf16x8*>(x2b + ((((size_t)(Rb+1)*4 + ks)*64 + lane) << 3));
      acc00 = __builtin_amdgcn_mfma_f32_16x16x32_bf16(a0, b0, acc00, 0, 0, 0);
      acc01 = __builtin_amdgcn_mfma_f32_16x16x32_bf16(a0, b1, acc01, 0, 0, 0);
      acc10 = __builtin_amdgcn_mfma_f32_16x16x32_bf16(a1, b0, acc10, 0, 0, 0);
      acc11 = __builtin_amdgcn_mfma_f32_16x16x32_bf16(a1, b1, acc11, 0, 0, 0);
    }

    // hoist target reads (static indices -> registers)
    float T2v[2][4], T1v[2];
#pragma unroll
    for (int tm = 0; tm < 2; ++tm)
#pragma unroll
      for (int rr = 0; rr < 4; ++rr) T2v[tm][rr] = sT2[wr*32 + tm*16 + rbase + rr];
    T1v[0] = sT1[wc*32 + fr];
    T1v[1] = sT1[wc*32 + 16 + fr];

    // C/D layout (m89/m91): col = lane&15, row = (lane>>4)*4 + reg
    auto dep = [&](const f32x4& a, int tm, int tn) {
      const int lj = wc*32 + tn*16 + fr;
      const float t1v = T1v[tn];
#pragma unroll
      for (int rr = 0; rr < 4; ++rr) {
        const int li = wr*32 + tm*16 + rbase + rr;
        bool pos = (T2v[tm][rr] * t1v > 0.0f);
        float uu = fmaf(a[rr], 102400.0f, 102400.5f);
        int   iu = (int)uu;
        int  idx = iu >> 10;
        idx = idx < 0 ? 0 : (idx > NSTEPS-1 ? NSTEPS-1 : idx);
        unsigned int pk = (1u << CNT_SHIFT) | (unsigned int)(iu & 1023);
        unsigned int* dst = whP + (pos ? 0 : NEGOFF) + idx;
        if (full || (lj > li)) atomicAdd(dst, pk);
      }
    };
    dep(acc00, 0, 0); dep(acc01, 0, 1);
    dep(acc10, 1, 0); dep(acc11, 1, 1);
  }
  __syncthreads();

  // unpack + flush once per sign table:
  // h[b] = cnt[b] - fr[b]/1024 + fr[b-1]/1024 ; h[200] = cnt[200] + fr[199]/1024
  float* gh = ghist + (size_t)(blockIdx.x & (NCOPY-1)) * (2*NSTEPS);
  if (tid < NSTEPS) {
    const int b = tid;
    const float inv = 1.0f / 1024.0f;
#pragma unroll
    for (int sg = 0; sg < 2; ++sg) {
      unsigned int cp = 0; float fp = 0.f, fpm1 = 0.f;
#pragma unroll
      for (int ww = 0; ww < NHIST; ++ww) {
        unsigned int vp = whist[sg][ww][b];
        cp += vp >> CNT_SHIFT;  fp += (float)(vp & FRAC_MASK);
        if (b > 0) fpm1 += (float)(whist[sg][ww][b-1] & FRAC_MASK);
      }
      float hv = (b == NSTEPS-1) ? ((float)cp + fpm1 * inv)
                                 : ((float)cp - fp * inv + fpm1 * inv);
      if (hv != 0.0f) atomicAdd(&gh[sg*NSTEPS + b], hv);
    }
  }
}

// ============ finalize: sum copies, cumsum pos, dot with neg ============
__global__ void finalize_kernel(const float* __restrict__ ghist,
                                float* __restrict__ out)
{
  __shared__ float hp[NSTEPS], hn[NSTEPS];
  const int tid = threadIdx.x;
  if (tid < NSTEPS) {
    float sp = 0.f, sn = 0.f;
#pragma unroll
    for (int c = 0; c < NCOPY; ++c) {
      sp += ghist[(size_t)c*(2*NSTEPS) + tid];
      sn += ghist[(size_t)c*(2*NSTEPS) + NSTEPS + tid];
    }
    hp[tid] = sp; hn[tid] = sn;
  }
  __syncthreads();
  if (tid == 0) {
    const float TOT = 33550336.0f;            // N*(N-1)/2
    float np = 0.f;
    for (int b = 0; b < NSTEPS; ++b) np += hp[b];
    float nn = TOT - np;
    float ip = 1.0f / fmaxf(np, 1.0f);
    float in_ = 1.0f / fmaxf(nn, 1.0f);
    float cdf = 0.f, loss = 0.f;
    for (int b = 0; b < NSTEPS; ++b) {
      cdf  += hp[b] * ip;
      loss += hn[b] * in_ * cdf;
    }
    out[0] = loss;
  }
}

extern "C" void kernel_launch(void* const* d_in, const int* in_sizes, int n_in,
                              void* d_out, int out_size, void* d_ws, size_t ws_size,
                              hipStream_t stream) {
  const float* x1 = (const float*)d_in[0];
  const float* x2 = (const float*)d_in[1];
  const float* t1 = (const float*)d_in[2];
  const float* t2 = (const float*)d_in[3];
  float* out = (float*)d_out;

  const size_t BF_BYTES = (size_t)N_EMB * D_EMB * sizeof(unsigned short);  // 2 MB each
  char* p = (char*)d_ws;
  unsigned short* x1b   = (unsigned short*)p;   p += BF_BYTES;
  unsigned short* x2b   = (unsigned short*)p;   p += BF_BYTES;
  float*          ghist = (float*)p;

  convert_kernel<<<(2*N_EMB*D_EMB/8 + 255)/256, 256, 0, stream>>>(x1, x2, x1b, x2b, ghist);
  main_kernel<<<PGRID, 256, 0, stream>>>(x1b, x2b, t1, t2, ghist);
  finalize_kernel<<<1, 256, 0, stream>>>(ghist, out);
}